// Round 1
// 6636.074 us; speedup vs baseline: 2.3945x; 2.3945x over previous
//
#include <hip/hip_runtime.h>
#include <hip/hip_bf16.h>
#include <math.h>

#define NUM_HEADS 16
#define HEAD_DIM  128
#define SEQ       2048
#define DM        2048
#define BATCH     4
#define M_ROWS    (BATCH * SEQ)   // 8192

typedef short  short8 __attribute__((ext_vector_type(8)));
typedef float  f32x4  __attribute__((ext_vector_type(4)));

__device__ inline unsigned short f2bf(float f) {
    union { float f; unsigned u; } x; x.f = f;
    unsigned r = x.u + 0x7FFF + ((x.u >> 16) & 1);   // RNE
    return (unsigned short)(r >> 16);
}

__device__ inline float bf2f(unsigned short u) {
    union { unsigned u; float f; } x; x.u = ((unsigned)u) << 16;
    return x.f;
}

// Simple correctness-first GEMM: C = A(M,K) * B(N,K)^T, fp32 compute.
// A: either f32 row-major (Af) or bf16 [b,h,s,d]-gather (Ag, for final proj).
// B: f32 row-major [N,K] ('nm' indexing -> B[col][k]).
// mode 0: C = Cf, f32 row-major [M,N]
// mode 1: C = Cb, bf16 scatter [b,h,s,d]
// mode 2: mode 1 + interleaved RoPE
// mode 3: bf16 scatter TRANSPOSED [b,h,d,s]  (for V: makes PV B-frags contiguous)
__global__ __launch_bounds__(256)
void sgemm(const float* __restrict__ Af, const unsigned short* __restrict__ Ag,
           const float* __restrict__ B, unsigned short* __restrict__ Cb,
           float* __restrict__ Cf, int mode) {
    __shared__ float As[64][17];
    __shared__ float Bs[64][17];
    const int tid = threadIdx.x;
    const int tx = tid & 15, ty = tid >> 4;
    const int tm = blockIdx.y * 64, tn = blockIdx.x * 64;
    const int lr = tid >> 2;          // 0..63: tile row to load
    const int lc = (tid & 3) * 4;     // 0,4,8,12: k offset to load

    float acc[4][4] = {};

    for (int k0 = 0; k0 < DM; k0 += 16) {
        // stage A
        if (Ag) {
            const int row = tm + lr;
            const int b = row >> 11, s = row & (SEQ - 1);
            const int k = k0 + lc;
            const int h = k >> 7, dd = k & (HEAD_DIM - 1);
            const ushort4 u = *(const ushort4*)&Ag[(((size_t)b * NUM_HEADS + h) * SEQ + s) * HEAD_DIM + dd];
            As[lr][lc + 0] = bf2f(u.x); As[lr][lc + 1] = bf2f(u.y);
            As[lr][lc + 2] = bf2f(u.z); As[lr][lc + 3] = bf2f(u.w);
        } else {
            const float4 v = *(const float4*)&Af[(size_t)(tm + lr) * DM + k0 + lc];
            As[lr][lc + 0] = v.x; As[lr][lc + 1] = v.y;
            As[lr][lc + 2] = v.z; As[lr][lc + 3] = v.w;
        }
        // stage B
        {
            const float4 w = *(const float4*)&B[(size_t)(tn + lr) * DM + k0 + lc];
            Bs[lr][lc + 0] = w.x; Bs[lr][lc + 1] = w.y;
            Bs[lr][lc + 2] = w.z; Bs[lr][lc + 3] = w.w;
        }
        __syncthreads();
        #pragma unroll
        for (int kk = 0; kk < 16; ++kk) {
            float a[4], bb[4];
            #pragma unroll
            for (int i = 0; i < 4; ++i) a[i] = As[ty * 4 + i][kk];
            #pragma unroll
            for (int j = 0; j < 4; ++j) bb[j] = Bs[tx * 4 + j][kk];
            #pragma unroll
            for (int i = 0; i < 4; ++i)
                #pragma unroll
                for (int j = 0; j < 4; ++j)
                    acc[i][j] += a[i] * bb[j];
        }
        __syncthreads();
    }

    // epilogue
    #pragma unroll
    for (int i = 0; i < 4; ++i) {
        const int row = tm + ty * 4 + i;
        float v[4];
        #pragma unroll
        for (int j = 0; j < 4; ++j) v[j] = acc[i][j];
        if (mode == 2) {
            const int s = row & (SEQ - 1);
            #pragma unroll
            for (int jp = 0; jp < 2; ++jp) {
                const int col0 = tn + tx * 4 + jp * 2;       // even col
                const int dcol = col0 & (HEAD_DIM - 1);      // even d index = 2*fi
                const int fi = dcol >> 1;                    // 0..63
                const float ang = (float)s * expf((float)fi * (-9.210340371976184f / 64.f));
                float sn, cs;
                sincosf(ang, &sn, &cs);
                const float e = v[jp * 2], o = v[jp * 2 + 1];
                v[jp * 2]     = e * cs - o * sn;             // rot_even
                v[jp * 2 + 1] = o * cs + e * sn;             // rot_odd
            }
        }
        #pragma unroll
        for (int j = 0; j < 4; ++j) {
            const int col = tn + tx * 4 + j;
            if (mode == 0) {
                Cf[(size_t)row * DM + col] = v[j];           // f32 output
            } else {
                const int b = row >> 11, s = row & (SEQ - 1);
                const int h = col >> 7, dd = col & (HEAD_DIM - 1);
                if (mode == 3)
                    Cb[(((size_t)b * NUM_HEADS + h) * HEAD_DIM + dd) * SEQ + s] = f2bf(v[j]);
                else
                    Cb[(((size_t)b * NUM_HEADS + h) * SEQ + s) * HEAD_DIM + dd] = f2bf(v[j]);
            }
        }
    }
}

// MFMA flash attention (causal), bf16 inputs, f32 accumulate.
// Q,K bf16 [bh, s, d]; Vt bf16 [bh, d, s] (TRANSPOSED); Y bf16 [bh, s, d].
// Y may alias Q: each wave reads only its own 16 Q rows (at start) and writes
// only those rows (at end).
// Block = 256 threads = 4 waves; each wave owns 16 query rows, loops KV in
// tiles of 64 keys. mfma_f32_16x16x32_bf16 throughout:
//   A-frag: lane holds row = lane&15,  k = (lane>>4)*8 + j  (8 consecutive k)
//   B-frag: lane holds col = lane&15,  k = (lane>>4)*8 + j
//   C/D  : lane holds col = lane&15, row = (lane>>4)*4 + i   [m89-verified]
// P (C-layout) -> A-layout transpose goes through a small padded LDS tile
// (wave-private, stride 72 ushorts = 144B: 16B-aligned, 2-way banks = free).
__global__ __launch_bounds__(256)
void mattn(const unsigned short* __restrict__ Q, const unsigned short* __restrict__ K,
           const unsigned short* __restrict__ Vt, unsigned short* __restrict__ Y) {
    __shared__ __align__(16) unsigned short Plds[4][16][72];
    const int tid = threadIdx.x, wave = tid >> 6, lane = tid & 63;
    const int lo = lane & 15, hi = lane >> 4;
    const int bh = blockIdx.y;
    const int q0 = blockIdx.x * 64 + wave * 16;
    const size_t baseQ = (size_t)bh * SEQ * HEAD_DIM;
    const size_t baseV = (size_t)bh * HEAD_DIM * SEQ;   // transposed layout

    // Q A-frags, 4 chunks of k=32: d = c*32 + hi*8 .. +8, row = q0+lo
    short8 qf[4];
    {
        const unsigned short* qrow = Q + baseQ + (size_t)(q0 + lo) * HEAD_DIM + hi * 8;
        #pragma unroll
        for (int c = 0; c < 4; ++c) qf[c] = *(const short8*)(qrow + c * 32);
    }

    f32x4 o[8];                       // O accum: 8 d-tiles of 16 cols
    #pragma unroll
    for (int dt = 0; dt < 8; ++dt) o[dt] = (f32x4){0.f, 0.f, 0.f, 0.f};
    float m[4], l[4];
    #pragma unroll
    for (int i = 0; i < 4; ++i) { m[i] = -1e30f; l[i] = 0.f; }

    // scale folded into log2 domain: exp(x*s) = exp2(x*s*log2e)
    const float kscale = 0.08838834764831845f * 1.4426950408889634f;
    const int ntiles = q0 / 64 + 1;   // only last tile needs the causal mask

    for (int kt = 0; kt < ntiles; ++kt) {
        const int kv0 = kt * 64;

        // ---- S = Q*K^T: 4 key-subtiles of 16 ----
        f32x4 s[4];
        #pragma unroll
        for (int t = 0; t < 4; ++t) {
            f32x4 acc = {0.f, 0.f, 0.f, 0.f};
            const unsigned short* krow =
                K + baseQ + (size_t)(kv0 + t * 16 + lo) * HEAD_DIM + hi * 8;
            #pragma unroll
            for (int c = 0; c < 4; ++c) {
                short8 kf = *(const short8*)(krow + c * 32);
                acc = __builtin_amdgcn_mfma_f32_16x16x32_bf16(qf[c], kf, acc, 0, 0, 0);
            }
            s[t] = acc;
        }

        // ---- scale + causal mask (C-layout: row = hi*4+i, col = t*16+lo) ----
        const bool diag = (kv0 + 64 > q0);
        #pragma unroll
        for (int t = 0; t < 4; ++t)
            #pragma unroll
            for (int i = 0; i < 4; ++i) {
                float v = s[t][i] * kscale;
                if (diag && (kv0 + t * 16 + lo > q0 + hi * 4 + i)) v = -1e30f;
                s[t][i] = v;
            }

        // ---- online softmax: row max (reduce over 16 cols = 16-lane group) ----
        float corr[4];
        #pragma unroll
        for (int i = 0; i < 4; ++i) {
            float v = fmaxf(fmaxf(s[0][i], s[1][i]), fmaxf(s[2][i], s[3][i]));
            v = fmaxf(v, __shfl_xor(v, 1, 64));
            v = fmaxf(v, __shfl_xor(v, 2, 64));
            v = fmaxf(v, __shfl_xor(v, 4, 64));
            v = fmaxf(v, __shfl_xor(v, 8, 64));
            const float mn = fmaxf(m[i], v);
            corr[i] = exp2f(m[i] - mn);
            m[i] = mn;
        }

        // ---- P = exp2(s - m): accumulate row-sum, spill bf16 P to LDS ----
        float rs[4] = {0.f, 0.f, 0.f, 0.f};
        #pragma unroll
        for (int t = 0; t < 4; ++t)
            #pragma unroll
            for (int i = 0; i < 4; ++i) {
                const float p = exp2f(s[t][i] - m[i]);
                rs[i] += p;
                Plds[wave][hi * 4 + i][t * 16 + lo] = f2bf(p);
            }
        #pragma unroll
        for (int i = 0; i < 4; ++i) {
            float v = rs[i];
            v += __shfl_xor(v, 1, 64);
            v += __shfl_xor(v, 2, 64);
            v += __shfl_xor(v, 4, 64);
            v += __shfl_xor(v, 8, 64);
            l[i] = l[i] * corr[i] + v;
        }

        // ---- rescale O by corr ----
        #pragma unroll
        for (int dt = 0; dt < 8; ++dt)
            #pragma unroll
            for (int i = 0; i < 4; ++i) o[dt][i] *= corr[i];

        // ---- P A-frags back from LDS (wave-private; compiler orders via lgkmcnt) ----
        short8 pa[2];
        #pragma unroll
        for (int ks = 0; ks < 2; ++ks)
            pa[ks] = *(const short8*)&Plds[wave][lo][ks * 32 + hi * 8];

        // ---- O += P * V  (V^T rows give contiguous 8-key B-frags) ----
        #pragma unroll
        for (int dt = 0; dt < 8; ++dt) {
            #pragma unroll
            for (int ks = 0; ks < 2; ++ks) {
                const unsigned short* vrow =
                    Vt + baseV + (size_t)(dt * 16 + lo) * SEQ + kv0 + ks * 32 + hi * 8;
                short8 vf = *(const short8*)vrow;
                o[dt] = __builtin_amdgcn_mfma_f32_16x16x32_bf16(pa[ks], vf, o[dt], 0, 0, 0);
            }
        }
    }

    // ---- epilogue: normalize and store (C-layout scatter) ----
    #pragma unroll
    for (int dt = 0; dt < 8; ++dt)
        #pragma unroll
        for (int i = 0; i < 4; ++i) {
            const float y = o[dt][i] / l[i];
            Y[baseQ + (size_t)(q0 + hi * 4 + i) * HEAD_DIM + dt * 16 + lo] = f2bf(y);
        }
}

extern "C" void kernel_launch(void* const* d_in, const int* in_sizes, int n_in,
                              void* d_out, int out_size, void* d_ws, size_t ws_size,
                              hipStream_t stream) {
    // ---- Runtime input identification (robust to ordering surprises) ----
    int xi = -1, pi = -1, wi[4] = {-1, -1, -1, -1};
    int nw = 0;
    for (int i = 0; i < n_in && i < 8; ++i) {
        const long long sz = in_sizes[i];
        if (sz == 16777216) xi = i;
        else if (sz == 2048) pi = i;
        else if (sz == 4194304 && nw < 4) wi[nw++] = i;
    }
    int iq, ik, iv, io;
    if (xi < 0 || nw < 4) {
        xi = 0; iq = 2; ik = 3; iv = 4; io = 5;   // documented dict order
    } else if (pi == 4 && xi == 5) {
        ik = wi[0]; io = wi[1]; iq = wi[2]; iv = wi[3];   // alphabetical
    } else {
        iq = wi[0]; ik = wi[1]; iv = wi[2]; io = wi[3];   // dict order
    }

    const float* x  = (const float*)d_in[xi];
    const float* Wq = (const float*)d_in[iq];
    const float* Wk = (const float*)d_in[ik];
    const float* Wv = (const float*)d_in[iv];
    const float* Wo = (const float*)d_in[io];
    float* out = (float*)d_out;

    // ws (ushorts): [Qb | Kb | Vt], 32 MiB each. Y aliases Qb.
    unsigned short* ws16 = (unsigned short*)d_ws;
    unsigned short* Qb = ws16;
    unsigned short* Kb = Qb + (1ull << 24);
    unsigned short* Vt = Kb + (1ull << 24);

    dim3 blk(256);
    dim3 gg(DM / 64, M_ROWS / 64);   // (32, 128)

    sgemm<<<gg, blk, 0, stream>>>(x, nullptr, Wq, Qb, nullptr, 2);   // Q + RoPE
    sgemm<<<gg, blk, 0, stream>>>(x, nullptr, Wk, Kb, nullptr, 2);   // K + RoPE
    sgemm<<<gg, blk, 0, stream>>>(x, nullptr, Wv, Vt, nullptr, 3);   // V, transposed
    mattn<<<dim3(SEQ / 64, BATCH * NUM_HEADS), blk, 0, stream>>>(Qb, Kb, Vt, Qb);
    sgemm<<<gg, blk, 0, stream>>>(nullptr, Qb, Wo, nullptr, out, 0); // out proj (f32)
}

// Round 2
// 2744.608 us; speedup vs baseline: 5.7896x; 2.4179x over previous
//
#include <hip/hip_runtime.h>
#include <hip/hip_bf16.h>
#include <math.h>

#define NUM_HEADS 16
#define HEAD_DIM  128
#define SEQ       2048
#define DM        2048
#define BATCH     4
#define M_ROWS    (BATCH * SEQ)   // 8192

typedef short  short8 __attribute__((ext_vector_type(8)));
typedef float  f32x4  __attribute__((ext_vector_type(4)));

__device__ inline unsigned short f2bf(float f) {
    union { float f; unsigned u; } x; x.f = f;
    unsigned r = x.u + 0x7FFF + ((x.u >> 16) & 1);   // RNE
    return (unsigned short)(r >> 16);
}

__device__ inline float bf2f(unsigned short u) {
    union { unsigned u; float f; } x; x.u = ((unsigned)u) << 16;
    return x.f;
}

// ---------------------------------------------------------------------------
// MFMA GEMM with fp32 emulation via bf16 hi/lo split ("bf16x2").
// C = A(M,K) * B(N,K)^T.
//   A: f32 row-major (Af) -> split into hi/lo, 3 passes: AhBh + AlBh + AhBl
//      OR bf16 [b,h,s,d]-gather (Ag, exact) -> 2 passes: A*Bh + A*Bl
//   B: f32 row-major [N,K], always split hi/lo.
// Tile 128x128, BK=32, 256 threads = 4 waves (2x2), each wave 64x64 via
// 4x4 frags of mfma_f32_16x16x32_bf16.
// Fragment mapping (HW-validated by the passing mattn kernel):
//   A/B frag: lane(lo=l&15,hi=l>>4) holds row/col=lo, k=hi*8..+8
//   C/D     : lane holds col=lo, row=hi*4+i
// modes: 0 f32 [M][N]; 1 bf16 scatter [b,h,s,d]; 2 =1+RoPE; 3 bf16 [b,h,d,s]
// LDS stride 40 ushorts (80B, 16B-aligned): frag ds_read_b128 is 2-way = free.
// ---------------------------------------------------------------------------
#define BKT  32
#define LDST 40

__global__ __launch_bounds__(256)
void mgemm(const float* __restrict__ Af, const unsigned short* __restrict__ Ag,
           const float* __restrict__ B, unsigned short* __restrict__ Cb,
           float* __restrict__ Cf, int mode) {
    __shared__ __align__(16) unsigned short AsH[128 * LDST];
    __shared__ __align__(16) unsigned short AsL[128 * LDST];
    __shared__ __align__(16) unsigned short BsH[128 * LDST];
    __shared__ __align__(16) unsigned short BsL[128 * LDST];

    const int tid = threadIdx.x;
    const int lane = tid & 63, wave = tid >> 6;
    const int lo = lane & 15, hi = lane >> 4;
    const int wm = wave >> 1, wn = wave & 1;          // wave tile (64x64)
    const int tm = blockIdx.y * 128, tn = blockIdx.x * 128;
    const bool split = (Ag == nullptr);

    const int sr = tid >> 3;          // 0..31 staging row
    const int sc = (tid & 7) * 4;     // 0..28 staging k offset

    f32x4 acc[4][4];
    #pragma unroll
    for (int mf = 0; mf < 4; ++mf)
        #pragma unroll
        for (int nf = 0; nf < 4; ++nf) acc[mf][nf] = (f32x4){0.f, 0.f, 0.f, 0.f};

    for (int k0 = 0; k0 < DM; k0 += BKT) {
        if (k0) __syncthreads();
        // ---- stage A (hi/lo split or bf16 gather) ----
        #pragma unroll
        for (int it = 0; it < 4; ++it) {
            const int r = it * 32 + sr;
            if (split) {
                const float4 v = *(const float4*)&Af[(size_t)(tm + r) * DM + k0 + sc];
                ushort4 h, l;
                h.x = f2bf(v.x); l.x = f2bf(v.x - bf2f(h.x));
                h.y = f2bf(v.y); l.y = f2bf(v.y - bf2f(h.y));
                h.z = f2bf(v.z); l.z = f2bf(v.z - bf2f(h.z));
                h.w = f2bf(v.w); l.w = f2bf(v.w - bf2f(h.w));
                *(ushort4*)&AsH[r * LDST + sc] = h;
                *(ushort4*)&AsL[r * LDST + sc] = l;
            } else {
                const int row = tm + r;
                const int b = row >> 11, s = row & (SEQ - 1);
                const int k = k0 + sc;
                const int hh = k >> 7, dd = k & (HEAD_DIM - 1);
                const ushort4 u = *(const ushort4*)
                    &Ag[(((size_t)b * NUM_HEADS + hh) * SEQ + s) * HEAD_DIM + dd];
                *(ushort4*)&AsH[r * LDST + sc] = u;
            }
        }
        // ---- stage B (always hi/lo split) ----
        #pragma unroll
        for (int it = 0; it < 4; ++it) {
            const int r = it * 32 + sr;
            const float4 v = *(const float4*)&B[(size_t)(tn + r) * DM + k0 + sc];
            ushort4 h, l;
            h.x = f2bf(v.x); l.x = f2bf(v.x - bf2f(h.x));
            h.y = f2bf(v.y); l.y = f2bf(v.y - bf2f(h.y));
            h.z = f2bf(v.z); l.z = f2bf(v.z - bf2f(h.z));
            h.w = f2bf(v.w); l.w = f2bf(v.w - bf2f(h.w));
            *(ushort4*)&BsH[r * LDST + sc] = h;
            *(ushort4*)&BsL[r * LDST + sc] = l;
        }
        __syncthreads();

        // ---- compute: hi*hi (+ lo*hi) + hi*lo ----
        short8 a0[4], b0[4], tf[4];
        #pragma unroll
        for (int mf = 0; mf < 4; ++mf)
            a0[mf] = *(const short8*)&AsH[(wm * 64 + mf * 16 + lo) * LDST + hi * 8];
        #pragma unroll
        for (int nf = 0; nf < 4; ++nf)
            b0[nf] = *(const short8*)&BsH[(wn * 64 + nf * 16 + lo) * LDST + hi * 8];
        #pragma unroll
        for (int mf = 0; mf < 4; ++mf)
            #pragma unroll
            for (int nf = 0; nf < 4; ++nf)
                acc[mf][nf] = __builtin_amdgcn_mfma_f32_16x16x32_bf16(
                    a0[mf], b0[nf], acc[mf][nf], 0, 0, 0);
        if (split) {
            #pragma unroll
            for (int mf = 0; mf < 4; ++mf)
                tf[mf] = *(const short8*)&AsL[(wm * 64 + mf * 16 + lo) * LDST + hi * 8];
            #pragma unroll
            for (int mf = 0; mf < 4; ++mf)
                #pragma unroll
                for (int nf = 0; nf < 4; ++nf)
                    acc[mf][nf] = __builtin_amdgcn_mfma_f32_16x16x32_bf16(
                        tf[mf], b0[nf], acc[mf][nf], 0, 0, 0);
        }
        #pragma unroll
        for (int nf = 0; nf < 4; ++nf)
            tf[nf] = *(const short8*)&BsL[(wn * 64 + nf * 16 + lo) * LDST + hi * 8];
        #pragma unroll
        for (int mf = 0; mf < 4; ++mf)
            #pragma unroll
            for (int nf = 0; nf < 4; ++nf)
                acc[mf][nf] = __builtin_amdgcn_mfma_f32_16x16x32_bf16(
                    a0[mf], tf[nf], acc[mf][nf], 0, 0, 0);
    }

    // ---- epilogue ----
    const int r0 = tm + wm * 64, c0 = tn + wn * 64;
    #pragma unroll
    for (int mf = 0; mf < 4; ++mf) {
        #pragma unroll
        for (int nf = 0; nf < 4; ++nf) {
            const int col = c0 + nf * 16 + lo;
            if (mode == 0) {
                #pragma unroll
                for (int i = 0; i < 4; ++i) {
                    const int row = r0 + mf * 16 + hi * 4 + i;
                    Cf[(size_t)row * DM + col] = acc[mf][nf][i];
                }
            } else if (mode == 3) {
                const int row0 = r0 + mf * 16 + hi * 4;
                const int b = row0 >> 11, s0 = row0 & (SEQ - 1);
                const int hh = col >> 7, dd = col & (HEAD_DIM - 1);
                ushort4 u;
                u.x = f2bf(acc[mf][nf][0]); u.y = f2bf(acc[mf][nf][1]);
                u.z = f2bf(acc[mf][nf][2]); u.w = f2bf(acc[mf][nf][3]);
                *(ushort4*)&Cb[(((size_t)b * NUM_HEADS + hh) * HEAD_DIM + dd) * SEQ + s0] = u;
            } else {
                #pragma unroll
                for (int i = 0; i < 4; ++i) {
                    const int row = r0 + mf * 16 + hi * 4 + i;
                    const int s = row & (SEQ - 1);
                    float val = acc[mf][nf][i];
                    if (mode == 2) {
                        const float partner = __shfl_xor(val, 1, 64);
                        const int fi = (col & (HEAD_DIM - 1)) >> 1;
                        const float ang = (float)s *
                            expf((float)fi * (-9.210340371976184f / 64.f));
                        float sn, cs;
                        sincosf(ang, &sn, &cs);
                        if ((col & 1) == 0) val = val * cs - partner * sn;
                        else                val = val * cs + partner * sn;
                    }
                    const int b = row >> 11;
                    const int hh = col >> 7, dd = col & (HEAD_DIM - 1);
                    Cb[(((size_t)b * NUM_HEADS + hh) * SEQ + s) * HEAD_DIM + dd] = f2bf(val);
                }
            }
        }
    }
}

// MFMA flash attention (causal), bf16 inputs, f32 accumulate. (unchanged)
// Q,K bf16 [bh, s, d]; Vt bf16 [bh, d, s]; Y bf16 [bh, s, d], may alias Q.
__global__ __launch_bounds__(256)
void mattn(const unsigned short* __restrict__ Q, const unsigned short* __restrict__ K,
           const unsigned short* __restrict__ Vt, unsigned short* __restrict__ Y) {
    __shared__ __align__(16) unsigned short Plds[4][16][72];
    const int tid = threadIdx.x, wave = tid >> 6, lane = tid & 63;
    const int lo = lane & 15, hi = lane >> 4;
    const int bh = blockIdx.y;
    const int q0 = blockIdx.x * 64 + wave * 16;
    const size_t baseQ = (size_t)bh * SEQ * HEAD_DIM;
    const size_t baseV = (size_t)bh * HEAD_DIM * SEQ;   // transposed layout

    short8 qf[4];
    {
        const unsigned short* qrow = Q + baseQ + (size_t)(q0 + lo) * HEAD_DIM + hi * 8;
        #pragma unroll
        for (int c = 0; c < 4; ++c) qf[c] = *(const short8*)(qrow + c * 32);
    }

    f32x4 o[8];
    #pragma unroll
    for (int dt = 0; dt < 8; ++dt) o[dt] = (f32x4){0.f, 0.f, 0.f, 0.f};
    float m[4], l[4];
    #pragma unroll
    for (int i = 0; i < 4; ++i) { m[i] = -1e30f; l[i] = 0.f; }

    const float kscale = 0.08838834764831845f * 1.4426950408889634f;
    const int ntiles = q0 / 64 + 1;

    for (int kt = 0; kt < ntiles; ++kt) {
        const int kv0 = kt * 64;

        f32x4 s[4];
        #pragma unroll
        for (int t = 0; t < 4; ++t) {
            f32x4 acc = {0.f, 0.f, 0.f, 0.f};
            const unsigned short* krow =
                K + baseQ + (size_t)(kv0 + t * 16 + lo) * HEAD_DIM + hi * 8;
            #pragma unroll
            for (int c = 0; c < 4; ++c) {
                short8 kf = *(const short8*)(krow + c * 32);
                acc = __builtin_amdgcn_mfma_f32_16x16x32_bf16(qf[c], kf, acc, 0, 0, 0);
            }
            s[t] = acc;
        }

        const bool diag = (kv0 + 64 > q0);
        #pragma unroll
        for (int t = 0; t < 4; ++t)
            #pragma unroll
            for (int i = 0; i < 4; ++i) {
                float v = s[t][i] * kscale;
                if (diag && (kv0 + t * 16 + lo > q0 + hi * 4 + i)) v = -1e30f;
                s[t][i] = v;
            }

        float corr[4];
        #pragma unroll
        for (int i = 0; i < 4; ++i) {
            float v = fmaxf(fmaxf(s[0][i], s[1][i]), fmaxf(s[2][i], s[3][i]));
            v = fmaxf(v, __shfl_xor(v, 1, 64));
            v = fmaxf(v, __shfl_xor(v, 2, 64));
            v = fmaxf(v, __shfl_xor(v, 4, 64));
            v = fmaxf(v, __shfl_xor(v, 8, 64));
            const float mn = fmaxf(m[i], v);
            corr[i] = exp2f(m[i] - mn);
            m[i] = mn;
        }

        float rs[4] = {0.f, 0.f, 0.f, 0.f};
        #pragma unroll
        for (int t = 0; t < 4; ++t)
            #pragma unroll
            for (int i = 0; i < 4; ++i) {
                const float p = exp2f(s[t][i] - m[i]);
                rs[i] += p;
                Plds[wave][hi * 4 + i][t * 16 + lo] = f2bf(p);
            }
        #pragma unroll
        for (int i = 0; i < 4; ++i) {
            float v = rs[i];
            v += __shfl_xor(v, 1, 64);
            v += __shfl_xor(v, 2, 64);
            v += __shfl_xor(v, 4, 64);
            v += __shfl_xor(v, 8, 64);
            l[i] = l[i] * corr[i] + v;
        }

        #pragma unroll
        for (int dt = 0; dt < 8; ++dt)
            #pragma unroll
            for (int i = 0; i < 4; ++i) o[dt][i] *= corr[i];

        short8 pa[2];
        #pragma unroll
        for (int ks = 0; ks < 2; ++ks)
            pa[ks] = *(const short8*)&Plds[wave][lo][ks * 32 + hi * 8];

        #pragma unroll
        for (int dt = 0; dt < 8; ++dt) {
            #pragma unroll
            for (int ks = 0; ks < 2; ++ks) {
                const unsigned short* vrow =
                    Vt + baseV + (size_t)(dt * 16 + lo) * SEQ + kv0 + ks * 32 + hi * 8;
                short8 vf = *(const short8*)vrow;
                o[dt] = __builtin_amdgcn_mfma_f32_16x16x32_bf16(pa[ks], vf, o[dt], 0, 0, 0);
            }
        }
    }

    #pragma unroll
    for (int dt = 0; dt < 8; ++dt)
        #pragma unroll
        for (int i = 0; i < 4; ++i) {
            const float y = o[dt][i] / l[i];
            Y[baseQ + (size_t)(q0 + hi * 4 + i) * HEAD_DIM + dt * 16 + lo] = f2bf(y);
        }
}

extern "C" void kernel_launch(void* const* d_in, const int* in_sizes, int n_in,
                              void* d_out, int out_size, void* d_ws, size_t ws_size,
                              hipStream_t stream) {
    // ---- Runtime input identification (robust to ordering surprises) ----
    int xi = -1, pi = -1, wi[4] = {-1, -1, -1, -1};
    int nw = 0;
    for (int i = 0; i < n_in && i < 8; ++i) {
        const long long sz = in_sizes[i];
        if (sz == 16777216) xi = i;
        else if (sz == 2048) pi = i;
        else if (sz == 4194304 && nw < 4) wi[nw++] = i;
    }
    int iq, ik, iv, io;
    if (xi < 0 || nw < 4) {
        xi = 0; iq = 2; ik = 3; iv = 4; io = 5;   // documented dict order
    } else if (pi == 4 && xi == 5) {
        ik = wi[0]; io = wi[1]; iq = wi[2]; iv = wi[3];   // alphabetical
    } else {
        iq = wi[0]; ik = wi[1]; iv = wi[2]; io = wi[3];   // dict order
    }

    const float* x  = (const float*)d_in[xi];
    const float* Wq = (const float*)d_in[iq];
    const float* Wk = (const float*)d_in[ik];
    const float* Wv = (const float*)d_in[iv];
    const float* Wo = (const float*)d_in[io];
    float* out = (float*)d_out;

    // ws (ushorts): [Qb | Kb | Vt], 32 MiB each. Y aliases Qb.
    unsigned short* ws16 = (unsigned short*)d_ws;
    unsigned short* Qb = ws16;
    unsigned short* Kb = Qb + (1ull << 24);
    unsigned short* Vt = Kb + (1ull << 24);

    dim3 blk(256);
    dim3 gg(DM / 128, M_ROWS / 128);   // (16, 64)

    mgemm<<<gg, blk, 0, stream>>>(x, nullptr, Wq, Qb, nullptr, 2);   // Q + RoPE
    mgemm<<<gg, blk, 0, stream>>>(x, nullptr, Wk, Kb, nullptr, 2);   // K + RoPE
    mgemm<<<gg, blk, 0, stream>>>(x, nullptr, Wv, Vt, nullptr, 3);   // V, transposed
    mattn<<<dim3(SEQ / 64, BATCH * NUM_HEADS), blk, 0, stream>>>(Qb, Kb, Vt, Qb);
    mgemm<<<gg, blk, 0, stream>>>(nullptr, Qb, Wo, nullptr, out, 0); // out proj (f32)
}

// Round 3
// 2210.654 us; speedup vs baseline: 7.1880x; 1.2415x over previous
//
#include <hip/hip_runtime.h>
#include <hip/hip_bf16.h>
#include <math.h>

#define NUM_HEADS 16
#define HEAD_DIM  128
#define SEQ       2048
#define DM        2048
#define BATCH     4
#define M_ROWS    (BATCH * SEQ)   // 8192

typedef short  short8 __attribute__((ext_vector_type(8)));
typedef float  f32x4  __attribute__((ext_vector_type(4)));

__device__ inline unsigned short f2bf(float f) {
    union { float f; unsigned u; } x; x.f = f;
    unsigned r = x.u + 0x7FFF + ((x.u >> 16) & 1);   // RNE
    return (unsigned short)(r >> 16);
}

__device__ inline float bf2f(unsigned short u) {
    union { unsigned u; float f; } x; x.u = ((unsigned)u) << 16;
    return x.f;
}

// ---------------------------------------------------------------------------
// MFMA GEMM with fp32 emulation via bf16 hi/lo split ("bf16x2"). (unchanged)
// C = A(M,K) * B(N,K)^T.
//   A: f32 row-major (Af) -> split into hi/lo, 3 passes: AhBh + AlBh + AhBl
//      OR bf16 [b,h,s,d]-gather (Ag, exact) -> 2 passes: A*Bh + A*Bl
//   B: f32 row-major [N,K], always split hi/lo.
// Tile 128x128, BK=32, 256 threads = 4 waves (2x2), each wave 64x64 via
// 4x4 frags of mfma_f32_16x16x32_bf16.
// modes: 0 f32 [M][N]; 1 bf16 scatter [b,h,s,d]; 2 =1+RoPE; 3 bf16 [b,h,d,s]
// LDS stride 40 ushorts (80B, 16B-aligned): frag ds_read_b128 is 2-way = free.
// ---------------------------------------------------------------------------
#define BKT  32
#define LDST 40

__global__ __launch_bounds__(256)
void mgemm(const float* __restrict__ Af, const unsigned short* __restrict__ Ag,
           const float* __restrict__ B, unsigned short* __restrict__ Cb,
           float* __restrict__ Cf, int mode) {
    __shared__ __align__(16) unsigned short AsH[128 * LDST];
    __shared__ __align__(16) unsigned short AsL[128 * LDST];
    __shared__ __align__(16) unsigned short BsH[128 * LDST];
    __shared__ __align__(16) unsigned short BsL[128 * LDST];

    const int tid = threadIdx.x;
    const int lane = tid & 63, wave = tid >> 6;
    const int lo = lane & 15, hi = lane >> 4;
    const int wm = wave >> 1, wn = wave & 1;          // wave tile (64x64)
    const int tm = blockIdx.y * 128, tn = blockIdx.x * 128;
    const bool split = (Ag == nullptr);

    const int sr = tid >> 3;          // 0..31 staging row
    const int sc = (tid & 7) * 4;     // 0..28 staging k offset

    f32x4 acc[4][4];
    #pragma unroll
    for (int mf = 0; mf < 4; ++mf)
        #pragma unroll
        for (int nf = 0; nf < 4; ++nf) acc[mf][nf] = (f32x4){0.f, 0.f, 0.f, 0.f};

    for (int k0 = 0; k0 < DM; k0 += BKT) {
        if (k0) __syncthreads();
        // ---- stage A (hi/lo split or bf16 gather) ----
        #pragma unroll
        for (int it = 0; it < 4; ++it) {
            const int r = it * 32 + sr;
            if (split) {
                const float4 v = *(const float4*)&Af[(size_t)(tm + r) * DM + k0 + sc];
                ushort4 h, l;
                h.x = f2bf(v.x); l.x = f2bf(v.x - bf2f(h.x));
                h.y = f2bf(v.y); l.y = f2bf(v.y - bf2f(h.y));
                h.z = f2bf(v.z); l.z = f2bf(v.z - bf2f(h.z));
                h.w = f2bf(v.w); l.w = f2bf(v.w - bf2f(h.w));
                *(ushort4*)&AsH[r * LDST + sc] = h;
                *(ushort4*)&AsL[r * LDST + sc] = l;
            } else {
                const int row = tm + r;
                const int b = row >> 11, s = row & (SEQ - 1);
                const int k = k0 + sc;
                const int hh = k >> 7, dd = k & (HEAD_DIM - 1);
                const ushort4 u = *(const ushort4*)
                    &Ag[(((size_t)b * NUM_HEADS + hh) * SEQ + s) * HEAD_DIM + dd];
                *(ushort4*)&AsH[r * LDST + sc] = u;
            }
        }
        // ---- stage B (always hi/lo split) ----
        #pragma unroll
        for (int it = 0; it < 4; ++it) {
            const int r = it * 32 + sr;
            const float4 v = *(const float4*)&B[(size_t)(tn + r) * DM + k0 + sc];
            ushort4 h, l;
            h.x = f2bf(v.x); l.x = f2bf(v.x - bf2f(h.x));
            h.y = f2bf(v.y); l.y = f2bf(v.y - bf2f(h.y));
            h.z = f2bf(v.z); l.z = f2bf(v.z - bf2f(h.z));
            h.w = f2bf(v.w); l.w = f2bf(v.w - bf2f(h.w));
            *(ushort4*)&BsH[r * LDST + sc] = h;
            *(ushort4*)&BsL[r * LDST + sc] = l;
        }
        __syncthreads();

        // ---- compute: hi*hi (+ lo*hi) + hi*lo ----
        short8 a0[4], b0[4], tf[4];
        #pragma unroll
        for (int mf = 0; mf < 4; ++mf)
            a0[mf] = *(const short8*)&AsH[(wm * 64 + mf * 16 + lo) * LDST + hi * 8];
        #pragma unroll
        for (int nf = 0; nf < 4; ++nf)
            b0[nf] = *(const short8*)&BsH[(wn * 64 + nf * 16 + lo) * LDST + hi * 8];
        #pragma unroll
        for (int mf = 0; mf < 4; ++mf)
            #pragma unroll
            for (int nf = 0; nf < 4; ++nf)
                acc[mf][nf] = __builtin_amdgcn_mfma_f32_16x16x32_bf16(
                    a0[mf], b0[nf], acc[mf][nf], 0, 0, 0);
        if (split) {
            #pragma unroll
            for (int mf = 0; mf < 4; ++mf)
                tf[mf] = *(const short8*)&AsL[(wm * 64 + mf * 16 + lo) * LDST + hi * 8];
            #pragma unroll
            for (int mf = 0; mf < 4; ++mf)
                #pragma unroll
                for (int nf = 0; nf < 4; ++nf)
                    acc[mf][nf] = __builtin_amdgcn_mfma_f32_16x16x32_bf16(
                        tf[mf], b0[nf], acc[mf][nf], 0, 0, 0);
        }
        #pragma unroll
        for (int nf = 0; nf < 4; ++nf)
            tf[nf] = *(const short8*)&BsL[(wn * 64 + nf * 16 + lo) * LDST + hi * 8];
        #pragma unroll
        for (int mf = 0; mf < 4; ++mf)
            #pragma unroll
            for (int nf = 0; nf < 4; ++nf)
                acc[mf][nf] = __builtin_amdgcn_mfma_f32_16x16x32_bf16(
                    a0[mf], tf[nf], acc[mf][nf], 0, 0, 0);
    }

    // ---- epilogue ----
    const int r0 = tm + wm * 64, c0 = tn + wn * 64;
    #pragma unroll
    for (int mf = 0; mf < 4; ++mf) {
        #pragma unroll
        for (int nf = 0; nf < 4; ++nf) {
            const int col = c0 + nf * 16 + lo;
            if (mode == 0) {
                #pragma unroll
                for (int i = 0; i < 4; ++i) {
                    const int row = r0 + mf * 16 + hi * 4 + i;
                    Cf[(size_t)row * DM + col] = acc[mf][nf][i];
                }
            } else if (mode == 3) {
                const int row0 = r0 + mf * 16 + hi * 4;
                const int b = row0 >> 11, s0 = row0 & (SEQ - 1);
                const int hh = col >> 7, dd = col & (HEAD_DIM - 1);
                ushort4 u;
                u.x = f2bf(acc[mf][nf][0]); u.y = f2bf(acc[mf][nf][1]);
                u.z = f2bf(acc[mf][nf][2]); u.w = f2bf(acc[mf][nf][3]);
                *(ushort4*)&Cb[(((size_t)b * NUM_HEADS + hh) * HEAD_DIM + dd) * SEQ + s0] = u;
            } else {
                #pragma unroll
                for (int i = 0; i < 4; ++i) {
                    const int row = r0 + mf * 16 + hi * 4 + i;
                    const int s = row & (SEQ - 1);
                    float val = acc[mf][nf][i];
                    if (mode == 2) {
                        const float partner = __shfl_xor(val, 1, 64);
                        const int fi = (col & (HEAD_DIM - 1)) >> 1;
                        const float ang = (float)s *
                            expf((float)fi * (-9.210340371976184f / 64.f));
                        float sn, cs;
                        sincosf(ang, &sn, &cs);
                        if ((col & 1) == 0) val = val * cs - partner * sn;
                        else                val = val * cs + partner * sn;
                    }
                    const int b = row >> 11;
                    const int hh = col >> 7, dd = col & (HEAD_DIM - 1);
                    Cb[(((size_t)b * NUM_HEADS + hh) * SEQ + s) * HEAD_DIM + dd] = f2bf(val);
                }
            }
        }
    }
}

// ---------------------------------------------------------------------------
// MFMA flash attention (causal), bf16 inputs, f32 accumulate.
// Q,K bf16 [bh, s, d]; Vt bf16 [bh, d, s]; Y bf16 [bh, s, d], may alias Q
// (each row read only by its owner wave, written by it last).
// LOAD-BALANCED: grid.x = SEQ/128 = 16; block x processes q-tiles {x, 31-x}
// -> every block does exactly 33 KV tiles (vs 1..32 before). 1024 blocks x 4
// waves = 4096 waves; __launch_bounds__(256,4) keeps VGPR <= 128 so all
// blocks are co-resident -> no low-occupancy tail.
// V loads issued in batches of 8 ahead of their MFMAs to overlap softmax.
// ---------------------------------------------------------------------------
__global__ __launch_bounds__(256, 4)
void mattn(const unsigned short* __restrict__ Q, const unsigned short* __restrict__ K,
           const unsigned short* __restrict__ Vt, unsigned short* __restrict__ Y) {
    __shared__ __align__(16) unsigned short Plds[4][16][72];
    const int tid = threadIdx.x, wave = tid >> 6, lane = tid & 63;
    const int lo = lane & 15, hi = lane >> 4;
    const int bh = blockIdx.y;
    const size_t baseQ = (size_t)bh * SEQ * HEAD_DIM;
    const size_t baseV = (size_t)bh * HEAD_DIM * SEQ;   // transposed layout
    const float kscale = 0.08838834764831845f * 1.4426950408889634f;
    const int NB = SEQ / 64;                            // 32 q-tiles

    #pragma unroll 1
    for (int pass = 0; pass < 2; ++pass) {
        const int qt = pass ? (NB - 1 - blockIdx.x) : blockIdx.x;
        const int q0 = qt * 64 + wave * 16;

        short8 qf[4];
        {
            const unsigned short* qrow = Q + baseQ + (size_t)(q0 + lo) * HEAD_DIM + hi * 8;
            #pragma unroll
            for (int c = 0; c < 4; ++c) qf[c] = *(const short8*)(qrow + c * 32);
        }

        f32x4 o[8];
        #pragma unroll
        for (int dt = 0; dt < 8; ++dt) o[dt] = (f32x4){0.f, 0.f, 0.f, 0.f};
        float m[4], l[4];
        #pragma unroll
        for (int i = 0; i < 4; ++i) { m[i] = -1e30f; l[i] = 0.f; }

        const int ntiles = qt + 1;

        for (int kt = 0; kt < ntiles; ++kt) {
            const int kv0 = kt * 64;

            // ---- S = Q*K^T: 4 key-subtiles of 16 ----
            f32x4 s[4];
            #pragma unroll
            for (int t = 0; t < 4; ++t) {
                f32x4 acc = {0.f, 0.f, 0.f, 0.f};
                const unsigned short* krow =
                    K + baseQ + (size_t)(kv0 + t * 16 + lo) * HEAD_DIM + hi * 8;
                #pragma unroll
                for (int c = 0; c < 4; ++c) {
                    short8 kf = *(const short8*)(krow + c * 32);
                    acc = __builtin_amdgcn_mfma_f32_16x16x32_bf16(qf[c], kf, acc, 0, 0, 0);
                }
                s[t] = acc;
            }

            // ---- scale + causal mask (C-layout: row = hi*4+i, col = t*16+lo) ----
            const bool diag = (kv0 + 64 > q0);
            #pragma unroll
            for (int t = 0; t < 4; ++t)
                #pragma unroll
                for (int i = 0; i < 4; ++i) {
                    float v = s[t][i] * kscale;
                    if (diag && (kv0 + t * 16 + lo > q0 + hi * 4 + i)) v = -1e30f;
                    s[t][i] = v;
                }

            // ---- online softmax: row max over 16 cols ----
            float corr[4];
            #pragma unroll
            for (int i = 0; i < 4; ++i) {
                float v = fmaxf(fmaxf(s[0][i], s[1][i]), fmaxf(s[2][i], s[3][i]));
                v = fmaxf(v, __shfl_xor(v, 1, 64));
                v = fmaxf(v, __shfl_xor(v, 2, 64));
                v = fmaxf(v, __shfl_xor(v, 4, 64));
                v = fmaxf(v, __shfl_xor(v, 8, 64));
                const float mn = fmaxf(m[i], v);
                corr[i] = exp2f(m[i] - mn);
                m[i] = mn;
            }

            // ---- P = exp2(s - m): row-sum + bf16 spill to LDS ----
            float rs[4] = {0.f, 0.f, 0.f, 0.f};
            #pragma unroll
            for (int t = 0; t < 4; ++t)
                #pragma unroll
                for (int i = 0; i < 4; ++i) {
                    const float p = exp2f(s[t][i] - m[i]);
                    rs[i] += p;
                    Plds[wave][hi * 4 + i][t * 16 + lo] = f2bf(p);
                }
            #pragma unroll
            for (int i = 0; i < 4; ++i) {
                float v = rs[i];
                v += __shfl_xor(v, 1, 64);
                v += __shfl_xor(v, 2, 64);
                v += __shfl_xor(v, 4, 64);
                v += __shfl_xor(v, 8, 64);
                l[i] = l[i] * corr[i] + v;
            }

            // ---- rescale O ----
            #pragma unroll
            for (int dt = 0; dt < 8; ++dt)
                #pragma unroll
                for (int i = 0; i < 4; ++i) o[dt][i] *= corr[i];

            // ---- P A-frags from LDS (wave-private) ----
            short8 pa[2];
            #pragma unroll
            for (int ks = 0; ks < 2; ++ks)
                pa[ks] = *(const short8*)&Plds[wave][lo][ks * 32 + hi * 8];

            // ---- O += P * V: loads batched 8-ahead of their MFMAs ----
            #pragma unroll
            for (int dh = 0; dh < 2; ++dh) {
                short8 vf[8];
                #pragma unroll
                for (int q = 0; q < 8; ++q) {
                    const int dt = dh * 4 + (q >> 1), ks = q & 1;
                    vf[q] = *(const short8*)(Vt + baseV +
                        (size_t)(dt * 16 + lo) * SEQ + kv0 + ks * 32 + hi * 8);
                }
                #pragma unroll
                for (int q = 0; q < 8; ++q) {
                    const int dt = dh * 4 + (q >> 1), ks = q & 1;
                    o[dt] = __builtin_amdgcn_mfma_f32_16x16x32_bf16(
                        pa[ks], vf[q], o[dt], 0, 0, 0);
                }
            }
        }

        // ---- epilogue: normalize and store ----
        #pragma unroll
        for (int dt = 0; dt < 8; ++dt)
            #pragma unroll
            for (int i = 0; i < 4; ++i) {
                const float y = o[dt][i] / l[i];
                Y[baseQ + (size_t)(q0 + hi * 4 + i) * HEAD_DIM + dt * 16 + lo] = f2bf(y);
            }
    }
}

extern "C" void kernel_launch(void* const* d_in, const int* in_sizes, int n_in,
                              void* d_out, int out_size, void* d_ws, size_t ws_size,
                              hipStream_t stream) {
    // ---- Runtime input identification (robust to ordering surprises) ----
    int xi = -1, pi = -1, wi[4] = {-1, -1, -1, -1};
    int nw = 0;
    for (int i = 0; i < n_in && i < 8; ++i) {
        const long long sz = in_sizes[i];
        if (sz == 16777216) xi = i;
        else if (sz == 2048) pi = i;
        else if (sz == 4194304 && nw < 4) wi[nw++] = i;
    }
    int iq, ik, iv, io;
    if (xi < 0 || nw < 4) {
        xi = 0; iq = 2; ik = 3; iv = 4; io = 5;   // documented dict order
    } else if (pi == 4 && xi == 5) {
        ik = wi[0]; io = wi[1]; iq = wi[2]; iv = wi[3];   // alphabetical
    } else {
        iq = wi[0]; ik = wi[1]; iv = wi[2]; io = wi[3];   // dict order
    }

    const float* x  = (const float*)d_in[xi];
    const float* Wq = (const float*)d_in[iq];
    const float* Wk = (const float*)d_in[ik];
    const float* Wv = (const float*)d_in[iv];
    const float* Wo = (const float*)d_in[io];
    float* out = (float*)d_out;

    // ws (ushorts): [Qb | Kb | Vt], 32 MiB each. Y aliases Qb.
    unsigned short* ws16 = (unsigned short*)d_ws;
    unsigned short* Qb = ws16;
    unsigned short* Kb = Qb + (1ull << 24);
    unsigned short* Vt = Kb + (1ull << 24);

    dim3 blk(256);
    dim3 gg(DM / 128, M_ROWS / 128);   // (16, 64)

    mgemm<<<gg, blk, 0, stream>>>(x, nullptr, Wq, Qb, nullptr, 2);   // Q + RoPE
    mgemm<<<gg, blk, 0, stream>>>(x, nullptr, Wk, Kb, nullptr, 2);   // K + RoPE
    mgemm<<<gg, blk, 0, stream>>>(x, nullptr, Wv, Vt, nullptr, 3);   // V, transposed
    mattn<<<dim3(SEQ / 128, BATCH * NUM_HEADS), blk, 0, stream>>>(Qb, Kb, Vt, Qb);
    mgemm<<<gg, blk, 0, stream>>>(nullptr, Qb, Wo, nullptr, out, 0); // out proj (f32)
}

// Round 4
// 1619.064 us; speedup vs baseline: 9.8144x; 1.3654x over previous
//
#include <hip/hip_runtime.h>
#include <hip/hip_bf16.h>
#include <math.h>

#define NUM_HEADS 16
#define HEAD_DIM  128
#define SEQ       2048
#define DM        2048
#define BATCH     4
#define M_ROWS    (BATCH * SEQ)   // 8192

typedef short  short8 __attribute__((ext_vector_type(8)));
typedef float  f32x4  __attribute__((ext_vector_type(4)));

__device__ inline unsigned short f2bf(float f) {
    union { float f; unsigned u; } x; x.f = f;
    unsigned r = x.u + 0x7FFF + ((x.u >> 16) & 1);   // RNE
    return (unsigned short)(r >> 16);
}

__device__ inline float bf2f(unsigned short u) {
    union { unsigned u; float f; } x; x.u = ((unsigned)u) << 16;
    return x.f;
}

// ---------------------------------------------------------------------------
// splitk: fp32 -> bf16 hi/lo, done ONCE per element (was: per K-step per block
// inside mgemm = 64x redundant on B panels). Memory-bound, ~5-30us each.
// ---------------------------------------------------------------------------
__global__ __launch_bounds__(256)
void splitk(const float* __restrict__ src, unsigned short* __restrict__ dh,
            unsigned short* __restrict__ dl, int n4) {
    const int stride = gridDim.x * 256;
    for (int i = blockIdx.x * 256 + threadIdx.x; i < n4; i += stride) {
        const float4 v = ((const float4*)src)[i];
        ushort4 h, l;
        h.x = f2bf(v.x); l.x = f2bf(v.x - bf2f(h.x));
        h.y = f2bf(v.y); l.y = f2bf(v.y - bf2f(h.y));
        h.z = f2bf(v.z); l.z = f2bf(v.z - bf2f(h.z));
        h.w = f2bf(v.w); l.w = f2bf(v.w - bf2f(h.w));
        ((ushort4*)dh)[i] = h;
        ((ushort4*)dl)[i] = l;
    }
}

#define BKT  32
#define LDST 40

// ---------------------------------------------------------------------------
// mgemm2: pre-split bf16x2 MFMA GEMM. C = A(M,K) * B(N,K)^T.
//   A: (Ah,Al) bf16 hi/lo row-major, 3 passes AhBh+AlBh+AhBl
//      OR Ag bf16 [b,h,s,d]-gather (exact), 2 passes AgBh+AgBl
//   B: (Bh,Bl) bf16 hi/lo row-major [N][K].
// Tile 128x128, BK=32, 4 waves (2x2), wave 64x64 via 4x4 16x16x32 frags.
// Staging is now pure short8 copies (no conversion VALU in the K-loop).
// LDS stride 40 ushorts: 16B-aligned chunks, 2-way banks = free (proven).
// modes: 0 f32 [M][N]; 2 bf16 scatter [b,h,s,d] + RoPE; 3 bf16 [b,h,d,s]
// ---------------------------------------------------------------------------
__global__ __launch_bounds__(256)
void mgemm2(const unsigned short* __restrict__ Ah, const unsigned short* __restrict__ Al,
            const unsigned short* __restrict__ Ag,
            const unsigned short* __restrict__ Bh, const unsigned short* __restrict__ Bl,
            unsigned short* __restrict__ Cb, float* __restrict__ Cf, int mode) {
    __shared__ __align__(16) unsigned short AsH[128 * LDST];
    __shared__ __align__(16) unsigned short AsL[128 * LDST];
    __shared__ __align__(16) unsigned short BsH[128 * LDST];
    __shared__ __align__(16) unsigned short BsL[128 * LDST];

    const int tid = threadIdx.x;
    const int lane = tid & 63, wave = tid >> 6;
    const int lo = lane & 15, hi = lane >> 4;
    const int wm = wave >> 1, wn = wave & 1;
    const int tm = blockIdx.y * 128, tn = blockIdx.x * 128;
    const bool split = (Ag == nullptr);

    const int sr = tid >> 2;          // 0..63 staging row (two j-passes: +0,+64)
    const int sc = (tid & 3) * 8;     // 0,8,16,24 ushort offset (16B chunks)

    f32x4 acc[4][4];
    #pragma unroll
    for (int mf = 0; mf < 4; ++mf)
        #pragma unroll
        for (int nf = 0; nf < 4; ++nf) acc[mf][nf] = (f32x4){0.f, 0.f, 0.f, 0.f};

    for (int k0 = 0; k0 < DM; k0 += BKT) {
        if (k0) __syncthreads();
        #pragma unroll
        for (int j = 0; j < 2; ++j) {
            const int r = j * 64 + sr;
            if (split) {
                *(short8*)&AsH[r * LDST + sc] =
                    *(const short8*)&Ah[(size_t)(tm + r) * DM + k0 + sc];
                *(short8*)&AsL[r * LDST + sc] =
                    *(const short8*)&Al[(size_t)(tm + r) * DM + k0 + sc];
            } else {
                const int row = tm + r;
                const int b = row >> 11, s = row & (SEQ - 1);
                const int hh = k0 >> 7, dd = (k0 & (HEAD_DIM - 1)) + sc;
                *(short8*)&AsH[r * LDST + sc] = *(const short8*)
                    &Ag[(((size_t)b * NUM_HEADS + hh) * SEQ + s) * HEAD_DIM + dd];
            }
            *(short8*)&BsH[r * LDST + sc] =
                *(const short8*)&Bh[(size_t)(tn + r) * DM + k0 + sc];
            *(short8*)&BsL[r * LDST + sc] =
                *(const short8*)&Bl[(size_t)(tn + r) * DM + k0 + sc];
        }
        __syncthreads();

        short8 a0[4], b0[4], tf[4];
        #pragma unroll
        for (int mf = 0; mf < 4; ++mf)
            a0[mf] = *(const short8*)&AsH[(wm * 64 + mf * 16 + lo) * LDST + hi * 8];
        #pragma unroll
        for (int nf = 0; nf < 4; ++nf)
            b0[nf] = *(const short8*)&BsH[(wn * 64 + nf * 16 + lo) * LDST + hi * 8];
        #pragma unroll
        for (int mf = 0; mf < 4; ++mf)
            #pragma unroll
            for (int nf = 0; nf < 4; ++nf)
                acc[mf][nf] = __builtin_amdgcn_mfma_f32_16x16x32_bf16(
                    a0[mf], b0[nf], acc[mf][nf], 0, 0, 0);
        if (split) {
            #pragma unroll
            for (int mf = 0; mf < 4; ++mf)
                tf[mf] = *(const short8*)&AsL[(wm * 64 + mf * 16 + lo) * LDST + hi * 8];
            #pragma unroll
            for (int mf = 0; mf < 4; ++mf)
                #pragma unroll
                for (int nf = 0; nf < 4; ++nf)
                    acc[mf][nf] = __builtin_amdgcn_mfma_f32_16x16x32_bf16(
                        tf[mf], b0[nf], acc[mf][nf], 0, 0, 0);
        }
        #pragma unroll
        for (int nf = 0; nf < 4; ++nf)
            tf[nf] = *(const short8*)&BsL[(wn * 64 + nf * 16 + lo) * LDST + hi * 8];
        #pragma unroll
        for (int mf = 0; mf < 4; ++mf)
            #pragma unroll
            for (int nf = 0; nf < 4; ++nf)
                acc[mf][nf] = __builtin_amdgcn_mfma_f32_16x16x32_bf16(
                    a0[mf], tf[nf], acc[mf][nf], 0, 0, 0);
    }

    // ---- epilogue (identical to proven mgemm) ----
    const int r0 = tm + wm * 64, c0 = tn + wn * 64;
    #pragma unroll
    for (int mf = 0; mf < 4; ++mf) {
        #pragma unroll
        for (int nf = 0; nf < 4; ++nf) {
            const int col = c0 + nf * 16 + lo;
            if (mode == 0) {
                #pragma unroll
                for (int i = 0; i < 4; ++i) {
                    const int row = r0 + mf * 16 + hi * 4 + i;
                    Cf[(size_t)row * DM + col] = acc[mf][nf][i];
                }
            } else if (mode == 3) {
                const int row0 = r0 + mf * 16 + hi * 4;
                const int b = row0 >> 11, s0 = row0 & (SEQ - 1);
                const int hh = col >> 7, dd = col & (HEAD_DIM - 1);
                ushort4 u;
                u.x = f2bf(acc[mf][nf][0]); u.y = f2bf(acc[mf][nf][1]);
                u.z = f2bf(acc[mf][nf][2]); u.w = f2bf(acc[mf][nf][3]);
                *(ushort4*)&Cb[(((size_t)b * NUM_HEADS + hh) * HEAD_DIM + dd) * SEQ + s0] = u;
            } else {
                #pragma unroll
                for (int i = 0; i < 4; ++i) {
                    const int row = r0 + mf * 16 + hi * 4 + i;
                    const int s = row & (SEQ - 1);
                    float val = acc[mf][nf][i];
                    if (mode == 2) {
                        const float partner = __shfl_xor(val, 1, 64);
                        const int fi = (col & (HEAD_DIM - 1)) >> 1;
                        const float ang = (float)s *
                            expf((float)fi * (-9.210340371976184f / 64.f));
                        float sn, cs;
                        sincosf(ang, &sn, &cs);
                        if ((col & 1) == 0) val = val * cs - partner * sn;
                        else                val = val * cs + partner * sn;
                    }
                    const int b = row >> 11;
                    const int hh = col >> 7, dd = col & (HEAD_DIM - 1);
                    Cb[(((size_t)b * NUM_HEADS + hh) * SEQ + s) * HEAD_DIM + dd] = f2bf(val);
                }
            }
        }
    }
}

// ---------------------------------------------------------------------------
// mgemm (round-3 on-the-fly-split version): kept as FALLBACK when ws_size is
// too small for the pre-split buffers. Unchanged, harness-proven.
// ---------------------------------------------------------------------------
__global__ __launch_bounds__(256)
void mgemm(const float* __restrict__ Af, const unsigned short* __restrict__ Ag,
           const float* __restrict__ B, unsigned short* __restrict__ Cb,
           float* __restrict__ Cf, int mode) {
    __shared__ __align__(16) unsigned short AsH[128 * LDST];
    __shared__ __align__(16) unsigned short AsL[128 * LDST];
    __shared__ __align__(16) unsigned short BsH[128 * LDST];
    __shared__ __align__(16) unsigned short BsL[128 * LDST];

    const int tid = threadIdx.x;
    const int lane = tid & 63, wave = tid >> 6;
    const int lo = lane & 15, hi = lane >> 4;
    const int wm = wave >> 1, wn = wave & 1;
    const int tm = blockIdx.y * 128, tn = blockIdx.x * 128;
    const bool split = (Ag == nullptr);

    const int sr = tid >> 3;
    const int sc = (tid & 7) * 4;

    f32x4 acc[4][4];
    #pragma unroll
    for (int mf = 0; mf < 4; ++mf)
        #pragma unroll
        for (int nf = 0; nf < 4; ++nf) acc[mf][nf] = (f32x4){0.f, 0.f, 0.f, 0.f};

    for (int k0 = 0; k0 < DM; k0 += BKT) {
        if (k0) __syncthreads();
        #pragma unroll
        for (int it = 0; it < 4; ++it) {
            const int r = it * 32 + sr;
            if (split) {
                const float4 v = *(const float4*)&Af[(size_t)(tm + r) * DM + k0 + sc];
                ushort4 h, l;
                h.x = f2bf(v.x); l.x = f2bf(v.x - bf2f(h.x));
                h.y = f2bf(v.y); l.y = f2bf(v.y - bf2f(h.y));
                h.z = f2bf(v.z); l.z = f2bf(v.z - bf2f(h.z));
                h.w = f2bf(v.w); l.w = f2bf(v.w - bf2f(h.w));
                *(ushort4*)&AsH[r * LDST + sc] = h;
                *(ushort4*)&AsL[r * LDST + sc] = l;
            } else {
                const int row = tm + r;
                const int b = row >> 11, s = row & (SEQ - 1);
                const int k = k0 + sc;
                const int hh = k >> 7, dd = k & (HEAD_DIM - 1);
                const ushort4 u = *(const ushort4*)
                    &Ag[(((size_t)b * NUM_HEADS + hh) * SEQ + s) * HEAD_DIM + dd];
                *(ushort4*)&AsH[r * LDST + sc] = u;
            }
        }
        #pragma unroll
        for (int it = 0; it < 4; ++it) {
            const int r = it * 32 + sr;
            const float4 v = *(const float4*)&B[(size_t)(tn + r) * DM + k0 + sc];
            ushort4 h, l;
            h.x = f2bf(v.x); l.x = f2bf(v.x - bf2f(h.x));
            h.y = f2bf(v.y); l.y = f2bf(v.y - bf2f(h.y));
            h.z = f2bf(v.z); l.z = f2bf(v.z - bf2f(h.z));
            h.w = f2bf(v.w); l.w = f2bf(v.w - bf2f(h.w));
            *(ushort4*)&BsH[r * LDST + sc] = h;
            *(ushort4*)&BsL[r * LDST + sc] = l;
        }
        __syncthreads();

        short8 a0[4], b0[4], tf[4];
        #pragma unroll
        for (int mf = 0; mf < 4; ++mf)
            a0[mf] = *(const short8*)&AsH[(wm * 64 + mf * 16 + lo) * LDST + hi * 8];
        #pragma unroll
        for (int nf = 0; nf < 4; ++nf)
            b0[nf] = *(const short8*)&BsH[(wn * 64 + nf * 16 + lo) * LDST + hi * 8];
        #pragma unroll
        for (int mf = 0; mf < 4; ++mf)
            #pragma unroll
            for (int nf = 0; nf < 4; ++nf)
                acc[mf][nf] = __builtin_amdgcn_mfma_f32_16x16x32_bf16(
                    a0[mf], b0[nf], acc[mf][nf], 0, 0, 0);
        if (split) {
            #pragma unroll
            for (int mf = 0; mf < 4; ++mf)
                tf[mf] = *(const short8*)&AsL[(wm * 64 + mf * 16 + lo) * LDST + hi * 8];
            #pragma unroll
            for (int mf = 0; mf < 4; ++mf)
                #pragma unroll
                for (int nf = 0; nf < 4; ++nf)
                    acc[mf][nf] = __builtin_amdgcn_mfma_f32_16x16x32_bf16(
                        tf[mf], b0[nf], acc[mf][nf], 0, 0, 0);
        }
        #pragma unroll
        for (int nf = 0; nf < 4; ++nf)
            tf[nf] = *(const short8*)&BsL[(wn * 64 + nf * 16 + lo) * LDST + hi * 8];
        #pragma unroll
        for (int mf = 0; mf < 4; ++mf)
            #pragma unroll
            for (int nf = 0; nf < 4; ++nf)
                acc[mf][nf] = __builtin_amdgcn_mfma_f32_16x16x32_bf16(
                    a0[mf], tf[nf], acc[mf][nf], 0, 0, 0);
    }

    const int r0 = tm + wm * 64, c0 = tn + wn * 64;
    #pragma unroll
    for (int mf = 0; mf < 4; ++mf) {
        #pragma unroll
        for (int nf = 0; nf < 4; ++nf) {
            const int col = c0 + nf * 16 + lo;
            if (mode == 0) {
                #pragma unroll
                for (int i = 0; i < 4; ++i) {
                    const int row = r0 + mf * 16 + hi * 4 + i;
                    Cf[(size_t)row * DM + col] = acc[mf][nf][i];
                }
            } else if (mode == 3) {
                const int row0 = r0 + mf * 16 + hi * 4;
                const int b = row0 >> 11, s0 = row0 & (SEQ - 1);
                const int hh = col >> 7, dd = col & (HEAD_DIM - 1);
                ushort4 u;
                u.x = f2bf(acc[mf][nf][0]); u.y = f2bf(acc[mf][nf][1]);
                u.z = f2bf(acc[mf][nf][2]); u.w = f2bf(acc[mf][nf][3]);
                *(ushort4*)&Cb[(((size_t)b * NUM_HEADS + hh) * HEAD_DIM + dd) * SEQ + s0] = u;
            } else {
                #pragma unroll
                for (int i = 0; i < 4; ++i) {
                    const int row = r0 + mf * 16 + hi * 4 + i;
                    const int s = row & (SEQ - 1);
                    float val = acc[mf][nf][i];
                    if (mode == 2) {
                        const float partner = __shfl_xor(val, 1, 64);
                        const int fi = (col & (HEAD_DIM - 1)) >> 1;
                        const float ang = (float)s *
                            expf((float)fi * (-9.210340371976184f / 64.f));
                        float sn, cs;
                        sincosf(ang, &sn, &cs);
                        if ((col & 1) == 0) val = val * cs - partner * sn;
                        else                val = val * cs + partner * sn;
                    }
                    const int b = row >> 11;
                    const int hh = col >> 7, dd = col & (HEAD_DIM - 1);
                    Cb[(((size_t)b * NUM_HEADS + hh) * SEQ + s) * HEAD_DIM + dd] = f2bf(val);
                }
            }
        }
    }
}

// ---------------------------------------------------------------------------
// MFMA flash attention (causal), bf16, f32 accumulate. (round-3, unchanged)
// grid.x = 16; block x does q-tiles {x, 31-x} -> exactly 33 KV tiles each.
// ---------------------------------------------------------------------------
__global__ __launch_bounds__(256, 4)
void mattn(const unsigned short* __restrict__ Q, const unsigned short* __restrict__ K,
           const unsigned short* __restrict__ Vt, unsigned short* __restrict__ Y) {
    __shared__ __align__(16) unsigned short Plds[4][16][72];
    const int tid = threadIdx.x, wave = tid >> 6, lane = tid & 63;
    const int lo = lane & 15, hi = lane >> 4;
    const int bh = blockIdx.y;
    const size_t baseQ = (size_t)bh * SEQ * HEAD_DIM;
    const size_t baseV = (size_t)bh * HEAD_DIM * SEQ;
    const float kscale = 0.08838834764831845f * 1.4426950408889634f;
    const int NB = SEQ / 64;

    #pragma unroll 1
    for (int pass = 0; pass < 2; ++pass) {
        const int qt = pass ? (NB - 1 - blockIdx.x) : blockIdx.x;
        const int q0 = qt * 64 + wave * 16;

        short8 qf[4];
        {
            const unsigned short* qrow = Q + baseQ + (size_t)(q0 + lo) * HEAD_DIM + hi * 8;
            #pragma unroll
            for (int c = 0; c < 4; ++c) qf[c] = *(const short8*)(qrow + c * 32);
        }

        f32x4 o[8];
        #pragma unroll
        for (int dt = 0; dt < 8; ++dt) o[dt] = (f32x4){0.f, 0.f, 0.f, 0.f};
        float m[4], l[4];
        #pragma unroll
        for (int i = 0; i < 4; ++i) { m[i] = -1e30f; l[i] = 0.f; }

        const int ntiles = qt + 1;

        for (int kt = 0; kt < ntiles; ++kt) {
            const int kv0 = kt * 64;

            f32x4 s[4];
            #pragma unroll
            for (int t = 0; t < 4; ++t) {
                f32x4 acc = {0.f, 0.f, 0.f, 0.f};
                const unsigned short* krow =
                    K + baseQ + (size_t)(kv0 + t * 16 + lo) * HEAD_DIM + hi * 8;
                #pragma unroll
                for (int c = 0; c < 4; ++c) {
                    short8 kf = *(const short8*)(krow + c * 32);
                    acc = __builtin_amdgcn_mfma_f32_16x16x32_bf16(qf[c], kf, acc, 0, 0, 0);
                }
                s[t] = acc;
            }

            const bool diag = (kv0 + 64 > q0);
            #pragma unroll
            for (int t = 0; t < 4; ++t)
                #pragma unroll
                for (int i = 0; i < 4; ++i) {
                    float v = s[t][i] * kscale;
                    if (diag && (kv0 + t * 16 + lo > q0 + hi * 4 + i)) v = -1e30f;
                    s[t][i] = v;
                }

            float corr[4];
            #pragma unroll
            for (int i = 0; i < 4; ++i) {
                float v = fmaxf(fmaxf(s[0][i], s[1][i]), fmaxf(s[2][i], s[3][i]));
                v = fmaxf(v, __shfl_xor(v, 1, 64));
                v = fmaxf(v, __shfl_xor(v, 2, 64));
                v = fmaxf(v, __shfl_xor(v, 4, 64));
                v = fmaxf(v, __shfl_xor(v, 8, 64));
                const float mn = fmaxf(m[i], v);
                corr[i] = exp2f(m[i] - mn);
                m[i] = mn;
            }

            float rs[4] = {0.f, 0.f, 0.f, 0.f};
            #pragma unroll
            for (int t = 0; t < 4; ++t)
                #pragma unroll
                for (int i = 0; i < 4; ++i) {
                    const float p = exp2f(s[t][i] - m[i]);
                    rs[i] += p;
                    Plds[wave][hi * 4 + i][t * 16 + lo] = f2bf(p);
                }
            #pragma unroll
            for (int i = 0; i < 4; ++i) {
                float v = rs[i];
                v += __shfl_xor(v, 1, 64);
                v += __shfl_xor(v, 2, 64);
                v += __shfl_xor(v, 4, 64);
                v += __shfl_xor(v, 8, 64);
                l[i] = l[i] * corr[i] + v;
            }

            #pragma unroll
            for (int dt = 0; dt < 8; ++dt)
                #pragma unroll
                for (int i = 0; i < 4; ++i) o[dt][i] *= corr[i];

            short8 pa[2];
            #pragma unroll
            for (int ks = 0; ks < 2; ++ks)
                pa[ks] = *(const short8*)&Plds[wave][lo][ks * 32 + hi * 8];

            #pragma unroll
            for (int dh = 0; dh < 2; ++dh) {
                short8 vf[8];
                #pragma unroll
                for (int q = 0; q < 8; ++q) {
                    const int dt = dh * 4 + (q >> 1), ks = q & 1;
                    vf[q] = *(const short8*)(Vt + baseV +
                        (size_t)(dt * 16 + lo) * SEQ + kv0 + ks * 32 + hi * 8);
                }
                #pragma unroll
                for (int q = 0; q < 8; ++q) {
                    const int dt = dh * 4 + (q >> 1), ks = q & 1;
                    o[dt] = __builtin_amdgcn_mfma_f32_16x16x32_bf16(
                        pa[ks], vf[q], o[dt], 0, 0, 0);
                }
            }
        }

        #pragma unroll
        for (int dt = 0; dt < 8; ++dt)
            #pragma unroll
            for (int i = 0; i < 4; ++i) {
                const float y = o[dt][i] / l[i];
                Y[baseQ + (size_t)(q0 + hi * 4 + i) * HEAD_DIM + dt * 16 + lo] = f2bf(y);
            }
    }
}

extern "C" void kernel_launch(void* const* d_in, const int* in_sizes, int n_in,
                              void* d_out, int out_size, void* d_ws, size_t ws_size,
                              hipStream_t stream) {
    // ---- Runtime input identification (robust to ordering surprises) ----
    int xi = -1, pi = -1, wi[4] = {-1, -1, -1, -1};
    int nw = 0;
    for (int i = 0; i < n_in && i < 8; ++i) {
        const long long sz = in_sizes[i];
        if (sz == 16777216) xi = i;
        else if (sz == 2048) pi = i;
        else if (sz == 4194304 && nw < 4) wi[nw++] = i;
    }
    int iq, ik, iv, io;
    if (xi < 0 || nw < 4) {
        xi = 0; iq = 2; ik = 3; iv = 4; io = 5;   // documented dict order
    } else if (pi == 4 && xi == 5) {
        ik = wi[0]; io = wi[1]; iq = wi[2]; iv = wi[3];   // alphabetical
    } else {
        iq = wi[0]; ik = wi[1]; iv = wi[2]; io = wi[3];   // dict order
    }

    const float* x  = (const float*)d_in[xi];
    const float* Wq = (const float*)d_in[iq];
    const float* Wk = (const float*)d_in[ik];
    const float* Wv = (const float*)d_in[iv];
    const float* Wo = (const float*)d_in[io];
    float* out = (float*)d_out;

    unsigned short* ws16 = (unsigned short*)d_ws;
    unsigned short* Qb = ws16;                       // 1<<24 ushorts (32 MiB)
    unsigned short* Kb = Qb + (1ull << 24);
    unsigned short* Vt = Kb + (1ull << 24);

    dim3 blk(256);
    dim3 gg(DM / 128, M_ROWS / 128);   // (16, 64)
    dim3 ga(SEQ / 128, BATCH * NUM_HEADS);

    // Pre-split path needs: Qb,Kb,Vt,xh,xl (5 x 1<<24) + Wh,Wl (2 x 1<<22)
    // = 92,274,688 ushorts = 184,549,376 bytes.
    const size_t NEED = ((5ull << 24) + (2ull << 22)) * 2ull;
    if (ws_size >= NEED) {
        unsigned short* xh = Vt + (1ull << 24);
        unsigned short* xl = xh + (1ull << 24);
        unsigned short* Wh = xl + (1ull << 24);
        unsigned short* Wl = Wh + (1ull << 22);
        const int nx4 = (M_ROWS * DM) / 4;           // 4,194,304
        const int nw4 = (DM * DM) / 4;               // 1,048,576
        dim3 gs(1024);

        splitk<<<gs, blk, 0, stream>>>(x,  xh, xl, nx4);
        splitk<<<gs, blk, 0, stream>>>(Wq, Wh, Wl, nw4);
        mgemm2<<<gg, blk, 0, stream>>>(xh, xl, nullptr, Wh, Wl, Qb, nullptr, 2);
        splitk<<<gs, blk, 0, stream>>>(Wk, Wh, Wl, nw4);
        mgemm2<<<gg, blk, 0, stream>>>(xh, xl, nullptr, Wh, Wl, Kb, nullptr, 2);
        splitk<<<gs, blk, 0, stream>>>(Wv, Wh, Wl, nw4);
        mgemm2<<<gg, blk, 0, stream>>>(xh, xl, nullptr, Wh, Wl, Vt, nullptr, 3);
        mattn<<<ga, blk, 0, stream>>>(Qb, Kb, Vt, Qb);
        splitk<<<gs, blk, 0, stream>>>(Wo, Wh, Wl, nw4);
        mgemm2<<<gg, blk, 0, stream>>>(nullptr, nullptr, Qb, Wh, Wl, nullptr, out, 0);
    } else {
        // Fallback: round-3 proven path (on-the-fly split).
        mgemm<<<gg, blk, 0, stream>>>(x, nullptr, Wq, Qb, nullptr, 2);
        mgemm<<<gg, blk, 0, stream>>>(x, nullptr, Wk, Kb, nullptr, 2);
        mgemm<<<gg, blk, 0, stream>>>(x, nullptr, Wv, Vt, nullptr, 3);
        mattn<<<ga, blk, 0, stream>>>(Qb, Kb, Vt, Qb);
        mgemm<<<gg, blk, 0, stream>>>(nullptr, Qb, Wo, nullptr, out, 0);
    }
}